// Round 7
// baseline (10428.856 us; speedup 1.0000x reference)
//
#include <hip/hip_runtime.h>
#include <math.h>

// Problem constants
#define TT 512
#define BB 64
#define EE 300
#define HD 256
#define KK 20

// LLC (coherence-point) accessors: relaxed agent-scope atomics compile to
// cache-bypassing loads/stores — no fences, no L2 invalidates, and W/P stay
// L2-resident across all 512 steps.
__device__ __forceinline__ void stg_llc(float* p, float v) {
    __hip_atomic_store(p, v, __ATOMIC_RELAXED, __HIP_MEMORY_SCOPE_AGENT);
}
__device__ __forceinline__ unsigned long long ldg_llc_u64(const unsigned long long* p) {
    return __hip_atomic_load(p, __ATOMIC_RELAXED, __HIP_MEMORY_SCOPE_AGENT);
}
__device__ __forceinline__ int ldg_llc_i(const int* p) {
    return __hip_atomic_load(p, __ATOMIC_RELAXED, __HIP_MEMORY_SCOPE_AGENT);
}
__device__ __forceinline__ void stg_llc_i(int* p, int v) {
    __hip_atomic_store(p, v, __ATOMIC_RELAXED, __HIP_MEMORY_SCOPE_AGENT);
}

// ============================================================
// K1: fused embedding-gather + input projection GEMM (fp32)
// P layout: [slot][gate(0..1023)][row(64)]  (row innermost, R4-proven)
// ============================================================
__global__ __launch_bounds__(256) void proj_kernel(
    const int* __restrict__ sentence, const float* __restrict__ embed,
    const float* __restrict__ Wf_ih, const float* __restrict__ bf,
    const float* __restrict__ Wb_ih, const float* __restrict__ bb,
    float* __restrict__ Pf, float* __restrict__ Pb, int t0f, int t0b)
{
    __shared__ float As[32][BB];   // [k][b]
    __shared__ float Ws[32][64];   // [k][gate-local]
    const int s   = blockIdx.x;
    const int gb  = blockIdx.y;           // 0..31
    const int dir = gb >> 4;
    const int g0  = (gb & 15) * 64;
    const int tg  = dir ? (t0b + s) : (t0f + s);
    const int tid = threadIdx.x;
    const int tx = tid & 15, ty = tid >> 4;

    const int lrow = tid >> 2;
    const int kq   = tid & 3;
    const int word = sentence[lrow * TT + tg];
    const float* arow = embed + (size_t)word * EE;
    const float* Wih  = dir ? Wb_ih : Wf_ih;
    const float* bias = dir ? bb : bf;
    const float* wrow = Wih + (size_t)(g0 + lrow) * EE;

    float acc[4][4] = {};
    for (int k0 = 0; k0 < EE; k0 += 32) {
        __syncthreads();
        #pragma unroll
        for (int u = 0; u < 8; ++u) {
            const int k  = kq * 8 + u;
            const int kk = k0 + k;
            const bool ok = (kk < EE);
            As[k][lrow] = ok ? arow[kk] : 0.f;
            Ws[k][lrow] = ok ? wrow[kk] : 0.f;
        }
        __syncthreads();
        #pragma unroll
        for (int k = 0; k < 32; ++k) {
            const float4 a = *(const float4*)&As[k][ty * 4];
            const float4 w = *(const float4*)&Ws[k][tx * 4];
            acc[0][0] += a.x*w.x; acc[0][1] += a.x*w.y; acc[0][2] += a.x*w.z; acc[0][3] += a.x*w.w;
            acc[1][0] += a.y*w.x; acc[1][1] += a.y*w.y; acc[1][2] += a.y*w.z; acc[1][3] += a.y*w.w;
            acc[2][0] += a.z*w.x; acc[2][1] += a.z*w.y; acc[2][2] += a.z*w.z; acc[2][3] += a.z*w.w;
            acc[3][0] += a.w*w.x; acc[3][1] += a.w*w.y; acc[3][2] += a.w*w.z; acc[3][3] += a.w*w.w;
        }
    }
    float* Pp = (dir ? Pb : Pf) + (size_t)s * 1024 * BB;
    #pragma unroll
    for (int j = 0; j < 4; ++j) {
        const int g = g0 + tx * 4 + j;
        const float bv = bias[g];
        float4 v;
        v.x = acc[0][j] + bv; v.y = acc[1][j] + bv;
        v.z = acc[2][j] + bv; v.w = acc[3][j] + bv;
        *(float4*)(Pp + (size_t)g * BB + ty * 4) = v;
    }
}

// ============================================================
// K2: dim-partitioned bidirectional LSTM (R4 structure) with
// VECTORIZED COOPERATIVE h staging — the R4 killer was 256 scalar
// 4B LLC loads/thread; now: 32 pipelined 8B LLC loads/thread into LDS.
// 128 blocks × 256 threads; dir = blk&1; block owns 4 h-dims × 64 rows.
// W rows (16 KB/block) are wave-uniform scalar loads — L1/K$ resident,
// never invalidated (no fences).
// Sync: flag array, relaxed LLC ops only; __syncthreads() drains vmcnt
// so h is complete at the LLC before the flag is raised.
// ============================================================
__global__ __launch_bounds__(256) void lstm_kernel(
    const float* __restrict__ Pf, const float* __restrict__ Pb,
    const float* __restrict__ Wf_hh, const float* __restrict__ Wb_hh,
    const int* __restrict__ lengths,
    float* __restrict__ HF, float* __restrict__ HB,
    float* __restrict__ hx,       // [parity][dir][HD][BB] exchange (LLC)
    float* __restrict__ cbuf,     // [dir][HD][BB] cell state (cross-dispatch)
    int* __restrict__ flags, int step0, int nsteps)
{
    __shared__ __align__(16) float h_s[HD * BB];   // 64 KiB, h_s[k*64 + r]
    const int blk  = blockIdx.x;
    const int dir  = blk & 1;          // interleave dirs across XCDs
    const int dgrp = blk >> 1;         // 0..63
    const int tid  = threadIdx.x;
    const int r    = tid & 63;
    int d = dgrp * 4 + (tid >> 6);
    d = __builtin_amdgcn_readfirstlane(d);

    const float* Whh = dir ? Wb_hh : Wf_hh;
    const float* Wgi = Whh + (size_t)(0 * HD + d) * HD;
    const float* Wgf = Whh + (size_t)(1 * HD + d) * HD;
    const float* Wgg = Whh + (size_t)(2 * HD + d) * HD;
    const float* Wgo = Whh + (size_t)(3 * HD + d) * HD;
    const float* P   = dir ? Pb : Pf;
    float* Hout = dir ? HB : HF;
    const int len = lengths[r];
    int* myflags = flags + dir * 64;

    float c = cbuf[(size_t)dir * HD * BB + (size_t)d * BB + r];

    for (int u = 0; u < nsteps; ++u) {
        const int gs   = step0 + u;                 // global step index
        const int p    = dir ? (TT - 1 - gs) : gs;  // global time position
        const int slot = dir ? (nsteps - 1 - u) : u;

        // P loads: h-independent, issued before the wait so latency hides
        const float* Pp = P + (size_t)slot * 1024 * BB + r;
        float ai = Pp[(size_t)(0 * HD + d) * BB];
        float af = Pp[(size_t)(1 * HD + d) * BB];
        float ag = Pp[(size_t)(2 * HD + d) * BB];
        float ao = Pp[(size_t)(3 * HD + d) * BB];

        // wait: all 64 blocks of this direction finished step gs-1
        if (tid < 64) {
            while (true) {
                const int v = ldg_llc_i(&myflags[r]);
                if (__all(v >= gs)) break;
            }
        }
        __syncthreads();

        // cooperative staged load: 64 KB h from LLC -> LDS, 8B lanes, 32/thread
        {
            const unsigned long long* src = (const unsigned long long*)
                (hx + ((size_t)(((gs + 1) & 1) * 2 + dir)) * HD * BB);
            unsigned long long* dst = (unsigned long long*)h_s;
            #pragma unroll
            for (int j = 0; j < 32; ++j)
                dst[j * 256 + tid] = ldg_llc_u64(&src[j * 256 + tid]);
        }
        __syncthreads();

        // GEMV: 4 gate-rows of W (scalar/L1) x h column (LDS)
        #pragma unroll 4
        for (int k = 0; k < HD; k += 8) {
            float hv[8];
            #pragma unroll
            for (int j = 0; j < 8; ++j) hv[j] = h_s[(k + j) * BB + r];
            #pragma unroll
            for (int j = 0; j < 8; ++j) {
                ai = fmaf(hv[j], Wgi[k + j], ai);
                af = fmaf(hv[j], Wgf[k + j], af);
                ag = fmaf(hv[j], Wgg[k + j], ag);
                ao = fmaf(hv[j], Wgo[k + j], ao);
            }
        }

        const float ig = 1.f / (1.f + expf(-ai));
        const float fg = 1.f / (1.f + expf(-af));
        const float og = 1.f / (1.f + expf(-ao));
        const float gt = tanhf(ag);
        float cn = fg * c + ig * gt;
        float hn = og * tanhf(cn);
        if (dir) {   // bwd: row inactive until p < len (padded-t emissions unused)
            const bool v = (p < len);
            c  = v ? cn : c;
            hn = v ? hn : 0.f;
        } else {
            c = cn;
        }
        stg_llc(hx + ((size_t)((gs & 1) * 2 + dir)) * HD * BB + (size_t)d * BB + r, hn);
        Hout[((size_t)p * HD + d) * BB + r] = hn;    // [t][d][r], 256B/wave

        __syncthreads();   // vmcnt(0): h complete at LLC before flag
        if (tid == 0) stg_llc_i(&myflags[dgrp], gs + 1);
    }

    cbuf[(size_t)dir * HD * BB + (size_t)d * BB + r] = c;
}

// ============================================================
// K3: emissions = [hf|hb] @ W_out^T + b_out -> emis[t][b][20]
// H layout [t][d][b] (R4-proven).
// ============================================================
__global__ __launch_bounds__(256) void emis_kernel(
    const float* __restrict__ HF, const float* __restrict__ HB,
    const float* __restrict__ W_out, const float* __restrict__ b_out,
    float* __restrict__ emis)
{
    const int t = blockIdx.x;
    const int b = threadIdx.x & 63;
    int jg = threadIdx.x >> 6;
    jg = __builtin_amdgcn_readfirstlane(jg);

    float acc[5];
    #pragma unroll
    for (int u = 0; u < 5; ++u) acc[u] = b_out[jg + 4 * u];

    const float* hf = HF + (size_t)t * HD * BB + b;
    const float* hb = HB + (size_t)t * HD * BB + b;
    for (int k = 0; k < HD; ++k) {
        const float hv = hf[(size_t)k * BB];
        #pragma unroll
        for (int u = 0; u < 5; ++u)
            acc[u] = fmaf(hv, W_out[(size_t)(jg + 4 * u) * 512 + k], acc[u]);
    }
    for (int k = 0; k < HD; ++k) {
        const float hv = hb[(size_t)k * BB];
        #pragma unroll
        for (int u = 0; u < 5; ++u)
            acc[u] = fmaf(hv, W_out[(size_t)(jg + 4 * u) * 512 + HD + k], acc[u]);
    }
    #pragma unroll
    for (int u = 0; u < 5; ++u)
        emis[((size_t)t * BB + b) * KK + jg + 4 * u] = acc[u];
}

// ============================================================
// K4: Viterbi per batch row; exact first-max argmax; bp in LDS.
// ============================================================
__global__ __launch_bounds__(64) void viterbi_kernel(
    const float* __restrict__ emis, const int* __restrict__ lengths,
    const float* __restrict__ trans, const int* __restrict__ stop_id_p,
    float* __restrict__ out)
{
    __shared__ float tr[KK * KK];
    __shared__ float delta[KK], nd[KK];
    __shared__ unsigned char bp[TT][KK];
    const int b = blockIdx.x;
    const int tid = threadIdx.x;
    for (int i = tid; i < KK * KK; i += 64) tr[i] = trans[i];
    if (tid < KK) delta[tid] = 0.f;
    const int len = lengths[b];
    __syncthreads();

    for (int t = 0; t < TT; ++t) {
        if (tid < KK) {
            if (t < len) {
                float best = delta[0] + tr[tid * KK + 0];
                int am = 0;
                for (int p2 = 1; p2 < KK; ++p2) {
                    const float v = delta[p2] + tr[tid * KK + p2];
                    if (v > best) { best = v; am = p2; }
                }
                nd[tid] = best + emis[((size_t)t * BB + b) * KK + tid];
                bp[t][tid] = (unsigned char)am;
            } else {
                nd[tid] = delta[tid];
                bp[t][tid] = (unsigned char)tid;
            }
        }
        __syncthreads();
        if (tid < KK) delta[tid] = nd[tid];
        __syncthreads();
    }

    if (tid == 0) {
        const int stop_id = *stop_id_p;
        float best = delta[0] + tr[stop_id * KK + 0];
        int bl = 0;
        for (int j = 1; j < KK; ++j) {
            const float v = delta[j] + tr[stop_id * KK + j];
            if (v > best) { best = v; bl = j; }
        }
        out[b] = best;
        float* pout = out + BB + (size_t)b * (TT + 1);
        pout[TT] = (float)bl;
        int tag = bl;
        for (int t = TT - 1; t >= 0; --t) {
            tag = bp[t][tag];
            pout[t] = (float)tag;
        }
    }
}

// ============================================================
extern "C" void kernel_launch(void* const* d_in, const int* in_sizes, int n_in,
                              void* d_out, int out_size, void* d_ws, size_t ws_size,
                              hipStream_t stream) {
    const int*   sentence = (const int*)d_in[0];
    const int*   lengths  = (const int*)d_in[1];
    const int*   stop_id  = (const int*)d_in[3];
    const float* embed    = (const float*)d_in[4];
    const float* Wf_ih    = (const float*)d_in[5];
    const float* Wf_hh    = (const float*)d_in[6];
    const float* bf       = (const float*)d_in[7];
    const float* Wb_ih    = (const float*)d_in[8];
    const float* Wb_hh    = (const float*)d_in[9];
    const float* bb       = (const float*)d_in[10];
    const float* W_out    = (const float*)d_in[11];
    const float* b_out    = (const float*)d_in[12];
    const float* trans    = (const float*)d_in[13];
    float* out = (float*)d_out;

    const size_t hf_elems   = (size_t)TT * HD * BB;
    const size_t emis_elems = (size_t)TT * BB * KK;
    const size_t hx_elems   = (size_t)2 * 2 * HD * BB;   // parity x dir x HD x BB
    const size_t cbuf_elems = (size_t)2 * HD * BB;
    const size_t fixed_bytes = (2 * hf_elems + emis_elems + hx_elems + cbuf_elems) * 4
                             + (size_t)128 * 4;
    int CH = 0;
    const int cands[6] = {256, 128, 64, 32, 16, 8};
    for (int i = 0; i < 6; ++i) {
        const size_t need = fixed_bytes + 2ull * cands[i] * 1024 * BB * 4;
        if (need <= ws_size) { CH = cands[i]; break; }
    }
    if (CH == 0) return;   // ws too small: fail loudly, don't fault

    float* Pf    = (float*)d_ws;
    float* Pb    = Pf + (size_t)CH * 1024 * BB;
    float* HF    = Pb + (size_t)CH * 1024 * BB;
    float* HB    = HF + hf_elems;
    float* emis  = HB + hf_elems;
    float* hx    = emis + emis_elems;
    float* cbuf  = hx + hx_elems;
    int*   flags = (int*)(cbuf + cbuf_elems);

    // zero exchange buffers, cell state, flags (contiguous)
    hipMemsetAsync(hx, 0, (hx_elems + cbuf_elems) * 4 + (size_t)128 * 4, stream);

    const int nch = TT / CH;
    for (int c = 0; c < nch; ++c) {
        const int t0f = c * CH;
        const int t0b = TT - (c + 1) * CH;
        proj_kernel<<<dim3(CH, 32), 256, 0, stream>>>(
            sentence, embed, Wf_ih, bf, Wb_ih, bb, Pf, Pb, t0f, t0b);
        lstm_kernel<<<dim3(128), 256, 0, stream>>>(
            Pf, Pb, Wf_hh, Wb_hh, lengths, HF, HB, hx, cbuf, flags, c * CH, CH);
    }
    emis_kernel<<<dim3(TT), 256, 0, stream>>>(HF, HB, W_out, b_out, emis);
    viterbi_kernel<<<dim3(BB), 64, 0, stream>>>(emis, lengths, trans, stop_id, out);
}

// Round 8
// 5895.525 us; speedup vs baseline: 1.7689x; 1.7689x over previous
//
#include <hip/hip_runtime.h>
#include <math.h>

// Problem constants
#define TT 512
#define BB 64
#define EE 300
#define HD 256
#define KK 20
#define NG 1024        // gate rows per direction
#define DG 8           // dim-groups per direction
#define RG 4           // row-groups per direction
#define DPB 32         // dims per block
#define RPB 16         // rows per block
#define WSTRIDE 132    // LDS W row stride (floats), padded
#define HSTRIDE 260    // LDS h row stride (floats), padded
#define WOFF 0
#define HOFF (256 * WSTRIDE)                 // 33792 floats
#define LDS_FLOATS (HOFF + RPB * HSTRIDE)    // 37952 floats = 151808 B

// Relaxed agent-scope atomics = cache-bypassing LLC ops (no fences anywhere;
// W/P stay cache-resident). Proven correct in R4/R7 (absmax 0).
__device__ __forceinline__ int ldg_llc_i(const int* p) {
    return __hip_atomic_load(p, __ATOMIC_RELAXED, __HIP_MEMORY_SCOPE_AGENT);
}
__device__ __forceinline__ void stg_llc_i(int* p, int v) {
    __hip_atomic_store(p, v, __ATOMIC_RELAXED, __HIP_MEMORY_SCOPE_AGENT);
}
__device__ __forceinline__ unsigned long long ldg_llc_u64(const unsigned long long* p) {
    return __hip_atomic_load(p, __ATOMIC_RELAXED, __HIP_MEMORY_SCOPE_AGENT);
}
__device__ __forceinline__ void stg_llc_u64(unsigned long long* p, unsigned long long v) {
    __hip_atomic_store(p, v, __ATOMIC_RELAXED, __HIP_MEMORY_SCOPE_AGENT);
}

// ============================================================
// K1: fused embedding-gather + input projection GEMM (fp32)
// P layout: [slot][row(64)][gate(1024)] (gate innermost).
// ============================================================
__global__ __launch_bounds__(256) void proj_kernel(
    const int* __restrict__ sentence, const float* __restrict__ embed,
    const float* __restrict__ Wf_ih, const float* __restrict__ bf,
    const float* __restrict__ Wb_ih, const float* __restrict__ bb,
    float* __restrict__ Pf, float* __restrict__ Pb, int t0f, int t0b)
{
    __shared__ float As[32][BB];
    __shared__ float Ws[32][64];
    const int s   = blockIdx.x;
    const int gb  = blockIdx.y;
    const int dir = gb >> 4;
    const int g0  = (gb & 15) * 64;
    const int tg  = dir ? (t0b + s) : (t0f + s);
    const int tid = threadIdx.x;
    const int tx = tid & 15, ty = tid >> 4;

    const int lrow = tid >> 2;
    const int kq   = tid & 3;
    const int word = sentence[lrow * TT + tg];
    const float* arow = embed + (size_t)word * EE;
    const float* Wih  = dir ? Wb_ih : Wf_ih;
    const float* bias = dir ? bb : bf;
    const float* wrow = Wih + (size_t)(g0 + lrow) * EE;

    float acc[4][4] = {};
    for (int k0 = 0; k0 < EE; k0 += 32) {
        __syncthreads();
        #pragma unroll
        for (int u = 0; u < 8; ++u) {
            const int k  = kq * 8 + u;
            const int kk = k0 + k;
            const bool ok = (kk < EE);
            As[k][lrow] = ok ? arow[kk] : 0.f;
            Ws[k][lrow] = ok ? wrow[kk] : 0.f;
        }
        __syncthreads();
        #pragma unroll
        for (int k = 0; k < 32; ++k) {
            const float4 a = *(const float4*)&As[k][ty * 4];
            const float4 w = *(const float4*)&Ws[k][tx * 4];
            acc[0][0] += a.x*w.x; acc[0][1] += a.x*w.y; acc[0][2] += a.x*w.z; acc[0][3] += a.x*w.w;
            acc[1][0] += a.y*w.x; acc[1][1] += a.y*w.y; acc[1][2] += a.y*w.z; acc[1][3] += a.y*w.w;
            acc[2][0] += a.z*w.x; acc[2][1] += a.z*w.y; acc[2][2] += a.z*w.z; acc[2][3] += a.z*w.w;
            acc[3][0] += a.w*w.x; acc[3][1] += a.w*w.y; acc[3][2] += a.w*w.z; acc[3][3] += a.w*w.w;
        }
    }
    float* Pd = (dir ? Pb : Pf) + (size_t)s * BB * NG;
    const float4 bv = *(const float4*)&bias[g0 + tx * 4];
    #pragma unroll
    for (int i = 0; i < 4; ++i) {
        float4 v;
        v.x = acc[i][0] + bv.x; v.y = acc[i][1] + bv.y;
        v.z = acc[i][2] + bv.z; v.w = acc[i][3] + bv.w;
        *(float4*)(Pd + (size_t)(ty * 4 + i) * NG + g0 + tx * 4) = v;
    }
}

// ============================================================
// K2: 2D-partitioned bidirectional LSTM.
// 64 blocks x 256 threads. blk%8 = domain (dir*4 + row-group i) -> all 8
// peers (dim-groups j = blk/8) share one XCD. Block owns 16 rows x 32 dims.
// W slice (128 gate-rows x 256 k = 128 KB) preloaded to LDS once.
// Per step: poll 8 flags -> stage 16 KB h slice (LLC->LDS, coalesced 8B
// atomic loads) -> GEMV from LDS -> cell -> 2 KB h out (LLC) -> flag.
// Thread (gl = tid&31, rs = tid>>5): dims d = j*32+gl, rows 2rs, 2rs+1;
// computes all 4 gates inline (no gate round-trip), c in registers.
// ============================================================
__global__ __launch_bounds__(256) void lstm_kernel(
    const float* __restrict__ Pf, const float* __restrict__ Pb,
    const float* __restrict__ Wf_hh, const float* __restrict__ Wb_hh,
    const int* __restrict__ lengths,
    float* __restrict__ HF, float* __restrict__ HB,
    float* __restrict__ hx,      // [parity][dir][rg][dim 256][row 16]
    float* __restrict__ cbuf,    // [dir][dim 256][row 64]
    int* __restrict__ flags,     // [dir*4+rg][16] (one 64B line per domain)
    int step0, int nsteps)
{
    extern __shared__ float lds[];
    const int blk    = blockIdx.x;
    const int domain = blk & 7;          // dir*4 + i  (XCD residue)
    const int j      = blk >> 3;         // dim-group 0..7
    const int dir    = domain >> 2;
    const int i      = domain & 3;       // row-group
    const int tid    = threadIdx.x;
    const int gl     = tid & 31;
    const int rs     = tid >> 5;         // 0..7
    const int r0     = rs * 2;
    const int dg     = j * DPB + gl;     // global dim 0..255
    const int gr0    = i * RPB + r0;     // global row

    const float* Whh = dir ? Wb_hh : Wf_hh;
    const float* P   = dir ? Pb : Pf;
    float* Hout = dir ? HB : HF;
    int* myflags = flags + domain * 16;
    const int len0 = lengths[gr0], len1 = lengths[gr0 + 1];

    // ---- preload W slice: lds[k*WSTRIDE + gl*4 + gt] = Whh[gt*256+j*32+gl][k]
    for (int e = tid; e < 128 * 256; e += 256) {
        const int rl = e >> 8;           // 0..127 local gate-row
        const int k  = e & 255;
        const int gt = rl >> 5, gll = rl & 31;
        lds[k * WSTRIDE + gll * 4 + gt] =
            Whh[(size_t)(gt * 256 + j * DPB + gll) * HD + k];
    }

    // ---- cell state
    const float2 cin = *(const float2*)&cbuf[((size_t)dir * HD + dg) * BB + gr0];
    float c0 = cin.x, c1 = cin.y;
    __syncthreads();

    for (int u = 0; u < nsteps; ++u) {
        const int gs   = step0 + u;
        const int p    = dir ? (TT - 1 - gs) : gs;
        const int slot = dir ? (nsteps - 1 - u) : u;

        // P terms (h-independent): 8 loads issued before the wait
        const float* Pp = P + (size_t)slot * BB * NG + (size_t)i * RPB * NG + j * DPB + gl;
        const float pi0 = Pp[(size_t)r0 * NG + 0 * 256];
        const float pf0 = Pp[(size_t)r0 * NG + 1 * 256];
        const float pg0 = Pp[(size_t)r0 * NG + 2 * 256];
        const float po0 = Pp[(size_t)r0 * NG + 3 * 256];
        const float pi1 = Pp[(size_t)(r0 + 1) * NG + 0 * 256];
        const float pf1 = Pp[(size_t)(r0 + 1) * NG + 1 * 256];
        const float pg1 = Pp[(size_t)(r0 + 1) * NG + 2 * 256];
        const float po1 = Pp[(size_t)(r0 + 1) * NG + 3 * 256];

        // wait: all 8 peers (dim-groups) of this domain finished step gs-1
        if (tid < 64) {
            const int* fl = myflags + (tid & 7);
            while (true) {
                const int v = ldg_llc_i(fl);
                if (__all(v >= gs)) break;
            }
        }
        __syncthreads();

        // stage h slice (16 KB) LLC -> LDS, transposing [k][r] -> [r][k]
        {
            const unsigned long long* src = (const unsigned long long*)
                (hx + ((size_t)(((gs + 1) & 1) * 2 + dir) * RG + i) * (HD * RPB));
            const int kbase = tid >> 3, rp = tid & 7;
            #pragma unroll
            for (int it = 0; it < 8; ++it) {
                const int k = kbase + 32 * it;
                const unsigned long long v = ldg_llc_u64(&src[k * 8 + rp]);
                union { unsigned long long u; float f[2]; } cv; cv.u = v;
                lds[HOFF + (2 * rp) * HSTRIDE + k]     = cv.f[0];
                lds[HOFF + (2 * rp + 1) * HSTRIDE + k] = cv.f[1];
            }
        }
        __syncthreads();

        // GEMV from LDS: 4 gates x 2 rows per thread over k=256
        float ai0 = 0.f, af0 = 0.f, ag0 = 0.f, ao0 = 0.f;
        float ai1 = 0.f, af1 = 0.f, ag1 = 0.f, ao1 = 0.f;
        {
            const float* Wl = lds + gl * 4;
            const float* h0 = lds + HOFF + r0 * HSTRIDE;
            const float* h1 = h0 + HSTRIDE;
            #pragma unroll 2
            for (int k = 0; k < HD; k += 4) {
                const float4 w0 = *(const float4*)(Wl + (size_t)(k + 0) * WSTRIDE);
                const float4 w1 = *(const float4*)(Wl + (size_t)(k + 1) * WSTRIDE);
                const float4 w2 = *(const float4*)(Wl + (size_t)(k + 2) * WSTRIDE);
                const float4 w3 = *(const float4*)(Wl + (size_t)(k + 3) * WSTRIDE);
                const float4 ha = *(const float4*)(h0 + k);
                const float4 hb = *(const float4*)(h1 + k);
                ai0 = fmaf(w0.x, ha.x, ai0); af0 = fmaf(w0.y, ha.x, af0);
                ag0 = fmaf(w0.z, ha.x, ag0); ao0 = fmaf(w0.w, ha.x, ao0);
                ai0 = fmaf(w1.x, ha.y, ai0); af0 = fmaf(w1.y, ha.y, af0);
                ag0 = fmaf(w1.z, ha.y, ag0); ao0 = fmaf(w1.w, ha.y, ao0);
                ai0 = fmaf(w2.x, ha.z, ai0); af0 = fmaf(w2.y, ha.z, af0);
                ag0 = fmaf(w2.z, ha.z, ag0); ao0 = fmaf(w2.w, ha.z, ao0);
                ai0 = fmaf(w3.x, ha.w, ai0); af0 = fmaf(w3.y, ha.w, af0);
                ag0 = fmaf(w3.z, ha.w, ag0); ao0 = fmaf(w3.w, ha.w, ao0);
                ai1 = fmaf(w0.x, hb.x, ai1); af1 = fmaf(w0.y, hb.x, af1);
                ag1 = fmaf(w0.z, hb.x, ag1); ao1 = fmaf(w0.w, hb.x, ao1);
                ai1 = fmaf(w1.x, hb.y, ai1); af1 = fmaf(w1.y, hb.y, af1);
                ag1 = fmaf(w1.z, hb.y, ag1); ao1 = fmaf(w1.w, hb.y, ao1);
                ai1 = fmaf(w2.x, hb.z, ai1); af1 = fmaf(w2.y, hb.z, af1);
                ag1 = fmaf(w2.z, hb.z, ag1); ao1 = fmaf(w2.w, hb.z, ao1);
                ai1 = fmaf(w3.x, hb.w, ai1); af1 = fmaf(w3.y, hb.w, af1);
                ag1 = fmaf(w3.z, hb.w, ag1); ao1 = fmaf(w3.w, hb.w, ao1);
            }
        }

        // cell math (inline, both rows)
        const float ig0 = 1.f / (1.f + expf(-(ai0 + pi0)));
        const float fg0 = 1.f / (1.f + expf(-(af0 + pf0)));
        const float og0 = 1.f / (1.f + expf(-(ao0 + po0)));
        const float gt0 = tanhf(ag0 + pg0);
        float cn0 = fg0 * c0 + ig0 * gt0;
        float hn0 = og0 * tanhf(cn0);
        const float ig1 = 1.f / (1.f + expf(-(ai1 + pi1)));
        const float fg1 = 1.f / (1.f + expf(-(af1 + pf1)));
        const float og1 = 1.f / (1.f + expf(-(ao1 + po1)));
        const float gt1 = tanhf(ag1 + pg1);
        float cn1 = fg1 * c1 + ig1 * gt1;
        float hn1 = og1 * tanhf(cn1);
        if (dir) {                  // bwd rows inactive until p < len
            const bool v0 = (p < len0), v1 = (p < len1);
            c0 = v0 ? cn0 : c0;  hn0 = v0 ? hn0 : 0.f;
            c1 = v1 ? cn1 : c1;  hn1 = v1 ? hn1 : 0.f;
        } else {
            c0 = cn0; c1 = cn1;
        }

        // publish h (2 KB/block): packed 8B atomic store to LLC
        {
            union { float f[2]; unsigned long long u; } pk;
            pk.f[0] = hn0; pk.f[1] = hn1;
            unsigned long long* dst = (unsigned long long*)
                (hx + ((size_t)((gs & 1) * 2 + dir) * RG + i) * (HD * RPB) + dg * RPB + r0);
            stg_llc_u64(dst, pk.u);
        }
        // H for emissions: [t][d][b] layout, float2 per thread
        {
            float2 hv; hv.x = hn0; hv.y = hn1;
            *(float2*)&Hout[((size_t)p * HD + dg) * BB + gr0] = hv;
        }

        __syncthreads();   // vmcnt(0): h complete at LLC before flag
        if (tid == 0) stg_llc_i(&myflags[j], gs + 1);
    }

    float2 cout; cout.x = c0; cout.y = c1;
    *(float2*)&cbuf[((size_t)dir * HD + dg) * BB + gr0] = cout;
}

// ============================================================
// K3: emissions = [hf|hb] @ W_out^T + b_out -> emis[t][b][20]
// H layout [t][d][b].
// ============================================================
__global__ __launch_bounds__(256) void emis_kernel(
    const float* __restrict__ HF, const float* __restrict__ HB,
    const float* __restrict__ W_out, const float* __restrict__ b_out,
    float* __restrict__ emis)
{
    const int t = blockIdx.x;
    const int b = threadIdx.x & 63;
    int jg = threadIdx.x >> 6;
    jg = __builtin_amdgcn_readfirstlane(jg);

    float acc[5];
    #pragma unroll
    for (int u = 0; u < 5; ++u) acc[u] = b_out[jg + 4 * u];

    const float* hf = HF + (size_t)t * HD * BB + b;
    const float* hb = HB + (size_t)t * HD * BB + b;
    for (int k = 0; k < HD; ++k) {
        const float hv = hf[(size_t)k * BB];
        #pragma unroll
        for (int u = 0; u < 5; ++u)
            acc[u] = fmaf(hv, W_out[(size_t)(jg + 4 * u) * 512 + k], acc[u]);
    }
    for (int k = 0; k < HD; ++k) {
        const float hv = hb[(size_t)k * BB];
        #pragma unroll
        for (int u = 0; u < 5; ++u)
            acc[u] = fmaf(hv, W_out[(size_t)(jg + 4 * u) * 512 + HD + k], acc[u]);
    }
    #pragma unroll
    for (int u = 0; u < 5; ++u)
        emis[((size_t)t * BB + b) * KK + jg + 4 * u] = acc[u];
}

// ============================================================
// K4: Viterbi per batch row; exact first-max argmax; bp in LDS.
// ============================================================
__global__ __launch_bounds__(64) void viterbi_kernel(
    const float* __restrict__ emis, const int* __restrict__ lengths,
    const float* __restrict__ trans, const int* __restrict__ stop_id_p,
    float* __restrict__ out)
{
    __shared__ float tr[KK * KK];
    __shared__ float delta[KK], nd[KK];
    __shared__ unsigned char bp[TT][KK];
    const int b = blockIdx.x;
    const int tid = threadIdx.x;
    for (int i = tid; i < KK * KK; i += 64) tr[i] = trans[i];
    if (tid < KK) delta[tid] = 0.f;
    const int len = lengths[b];
    __syncthreads();

    for (int t = 0; t < TT; ++t) {
        if (tid < KK) {
            if (t < len) {
                float best = delta[0] + tr[tid * KK + 0];
                int am = 0;
                for (int p2 = 1; p2 < KK; ++p2) {
                    const float v = delta[p2] + tr[tid * KK + p2];
                    if (v > best) { best = v; am = p2; }
                }
                nd[tid] = best + emis[((size_t)t * BB + b) * KK + tid];
                bp[t][tid] = (unsigned char)am;
            } else {
                nd[tid] = delta[tid];
                bp[t][tid] = (unsigned char)tid;
            }
        }
        __syncthreads();
        if (tid < KK) delta[tid] = nd[tid];
        __syncthreads();
    }

    if (tid == 0) {
        const int stop_id = *stop_id_p;
        float best = delta[0] + tr[stop_id * KK + 0];
        int bl = 0;
        for (int jx = 1; jx < KK; ++jx) {
            const float v = delta[jx] + tr[stop_id * KK + jx];
            if (v > best) { best = v; bl = jx; }
        }
        out[b] = best;
        float* pout = out + BB + (size_t)b * (TT + 1);
        pout[TT] = (float)bl;
        int tag = bl;
        for (int t = TT - 1; t >= 0; --t) {
            tag = bp[t][tag];
            pout[t] = (float)tag;
        }
    }
}

// ============================================================
extern "C" void kernel_launch(void* const* d_in, const int* in_sizes, int n_in,
                              void* d_out, int out_size, void* d_ws, size_t ws_size,
                              hipStream_t stream) {
    const int*   sentence = (const int*)d_in[0];
    const int*   lengths  = (const int*)d_in[1];
    const int*   stop_id  = (const int*)d_in[3];
    const float* embed    = (const float*)d_in[4];
    const float* Wf_ih    = (const float*)d_in[5];
    const float* Wf_hh    = (const float*)d_in[6];
    const float* bf       = (const float*)d_in[7];
    const float* Wb_ih    = (const float*)d_in[8];
    const float* Wb_hh    = (const float*)d_in[9];
    const float* bb       = (const float*)d_in[10];
    const float* W_out    = (const float*)d_in[11];
    const float* b_out    = (const float*)d_in[12];
    const float* trans    = (const float*)d_in[13];
    float* out = (float*)d_out;

    const size_t hf_elems   = (size_t)TT * HD * BB;
    const size_t emis_elems = (size_t)TT * BB * KK;
    const size_t hx_elems   = (size_t)2 * 2 * RG * HD * RPB;  // 65536
    const size_t cbuf_elems = (size_t)2 * HD * BB;            // 32768
    const size_t flag_elems = (size_t)8 * 16;
    const size_t fixed_bytes = (2 * hf_elems + emis_elems + hx_elems + cbuf_elems + flag_elems) * 4;

    int CH = 0;
    const int cands[6] = {256, 128, 64, 32, 16, 8};
    for (int i = 0; i < 6; ++i) {
        const size_t need = fixed_bytes + 2ull * cands[i] * BB * NG * 4;
        if (need <= ws_size) { CH = cands[i]; break; }
    }
    if (CH == 0) return;

    float* Pf    = (float*)d_ws;
    float* Pb    = Pf + (size_t)CH * BB * NG;
    float* HF    = Pb + (size_t)CH * BB * NG;
    float* HB    = HF + hf_elems;
    float* emis  = HB + hf_elems;
    float* hx    = emis + emis_elems;
    float* cbuf  = hx + hx_elems;
    int*   flags = (int*)(cbuf + cbuf_elems);

    // allow >64KB dynamic LDS (idempotent host call; not a stream op)
    static bool attr_set = false;
    (void)attr_set;
    hipFuncSetAttribute((const void*)lstm_kernel,
                        hipFuncAttributeMaxDynamicSharedMemorySize,
                        LDS_FLOATS * 4);

    // zero hx (both parities), cbuf, flags — contiguous region
    hipMemsetAsync(hx, 0, (hx_elems + cbuf_elems + flag_elems) * 4, stream);

    const int nch = TT / CH;
    for (int c = 0; c < nch; ++c) {
        const int t0f = c * CH;
        const int t0b = TT - (c + 1) * CH;
        proj_kernel<<<dim3(CH, 32), 256, 0, stream>>>(
            sentence, embed, Wf_ih, bf, Wb_ih, bb, Pf, Pb, t0f, t0b);
        lstm_kernel<<<dim3(64), 256, LDS_FLOATS * 4, stream>>>(
            Pf, Pb, Wf_hh, Wb_hh, lengths, HF, HB, hx, cbuf, flags, c * CH, CH);
    }
    emis_kernel<<<dim3(TT), 256, 0, stream>>>(HF, HB, W_out, b_out, emis);
    viterbi_kernel<<<dim3(BB), 64, 0, stream>>>(emis, lengths, trans, stop_id, out);
}